// Round 1
// baseline (150.171 us; speedup 1.0000x reference)
//
#include <hip/hip_runtime.h>
#include <math.h>

#define BB 32
#define LL 128
#define DD 256
#define HH 1024   // 4*D

__device__ __forceinline__ float waveReduceSum(float v) {
#pragma unroll
    for (int m = 32; m >= 1; m >>= 1) v += __shfl_xor(v, m, 64);
    return v;
}
__device__ __forceinline__ float waveReduceMax(float v) {
#pragma unroll
    for (int m = 32; m >= 1; m >>= 1) v = fmaxf(v, __shfl_xor(v, m, 64));
    return v;
}

__device__ __forceinline__ float masked_we(float w) {
    return (fabsf(w) < 1e-7f) ? -1e7f : w;
}

__global__ __launch_bounds__(256) void fused_attn_pool_kernel(
    const float* __restrict__ a1, const int* __restrict__ len1,
    const float* __restrict__ a2, const int* __restrict__ len2,
    const float* __restrict__ fcw, const float* __restrict__ fcb,
    const float* __restrict__ ww, float* __restrict__ out)
{
    const int b    = blockIdx.x;
    const int tid  = threadIdx.x;
    const int wave = tid >> 6;
    const int lane = tid & 63;

    __shared__ __align__(16) float wws[DD];
    __shared__ float s1[LL], s2[LL];
    __shared__ float rs[LL], cs[LL];
    __shared__ __align__(16) float pooled[DD];
    __shared__ float red[4];
    __shared__ float gmax_s, dinv_s;

    const int l1 = len1[b];
    const int l2 = len2[b];

    wws[tid] = ww[tid];               // DD == blockDim == 256
    __syncthreads();

    const float* A1 = a1 + (size_t)b * LL * DD;
    const float* A2 = a2 + (size_t)b * LL * DD;

    // ---- phase 1: s1[i] = dot(A1 row i, ww), s2[j] = dot(A2 row j, ww) ----
    {
        const float w0 = wws[lane * 4 + 0], w1 = wws[lane * 4 + 1];
        const float w2 = wws[lane * 4 + 2], w3 = wws[lane * 4 + 3];
        for (int row = wave; row < LL; row += 4) {
            const float4 v = *(const float4*)(A1 + row * DD + lane * 4);
            float p = v.x * w0 + v.y * w1 + v.z * w2 + v.w * w3;
            p = waveReduceSum(p);
            if (lane == 0) s1[row] = p;
        }
        for (int row = wave; row < LL; row += 4) {
            const float4 v = *(const float4*)(A2 + row * DD + lane * 4);
            float p = v.x * w0 + v.y * w1 + v.z * w2 + v.w * w3;
            p = waveReduceSum(p);
            if (lane == 0) s2[row] = p;
        }
    }
    __syncthreads();

    // ---- phase 2: global max over all L*L masked scores ----
    {
        float m = -INFINITY;
        for (int n = tid; n < LL * LL; n += 256) {
            const int i = n >> 7, j = n & 127;
            float wem;
            if (i < l1 && j < l2) wem = masked_we(s1[i] - s2[j]);
            else                  wem = -1e7f;
            m = fmaxf(m, wem);
        }
        m = waveReduceMax(m);
        if (lane == 0) red[wave] = m;
    }
    __syncthreads();
    if (tid == 0)
        gmax_s = fmaxf(fmaxf(red[0], red[1]), fmaxf(red[2], red[3]));
    __syncthreads();
    const float gmax = gmax_s;

    // ---- phase 3: row sums r[i] (waves 0-1) and col sums c[j] (waves 2-3) ----
    if (tid < LL) {
        const int i = tid;
        float acc = 0.f;
        if (i < l1) {
            const float si = s1[i];
            for (int j = 0; j < l2; ++j)
                acc += expf(masked_we(si - s2[j]) - gmax);
        }
        rs[i] = acc;
    } else {
        const int j = tid - LL;
        float acc = 0.f;
        if (j < l2) {
            const float sj = s2[j];
            for (int i = 0; i < l1; ++i)
                acc += expf(masked_we(s1[i] - sj) - gmax);
        }
        cs[j] = acc;
    }
    __syncthreads();

    if (tid == 0) {
        float denom = 0.f;
        for (int i = 0; i < LL; ++i) denom += rs[i];
        // invalid entries all carry masked score -1e7 in the softmax denominator
        denom += (float)(LL * LL - l1 * l2) * expf(-1e7f - gmax);
        dinv_s = 1.0f / denom;
    }
    __syncthreads();
    const float dinv = dinv_s;

    // ---- phase 4: pooled[d] = (1/denom) * (sum_i r_i*A1[i,d] - sum_j c_j*A2[j,d]) ----
    {
        float p = 0.f;
        const int d0 = tid;
#pragma unroll 4
        for (int i = 0; i < LL; ++i)
            p += rs[i] * A1[i * DD + d0] - cs[i] * A2[i * DD + d0];
        pooled[d0] = p * dinv;
    }
    __syncthreads();

    // ---- phase 5: out[h] = tanh(dot(pooled, fcw[h]) + fcb[h]) ----
    {
        const float p0 = pooled[lane * 4 + 0], p1 = pooled[lane * 4 + 1];
        const float p2 = pooled[lane * 4 + 2], p3 = pooled[lane * 4 + 3];
        for (int h = wave; h < HH; h += 4) {
            const float4 wv = *(const float4*)(fcw + (size_t)h * DD + lane * 4);
            float p = wv.x * p0 + wv.y * p1 + wv.z * p2 + wv.w * p3;
            p = waveReduceSum(p);
            if (lane == 0) out[(size_t)b * HH + h] = tanhf(p + fcb[h]);
        }
    }
}

extern "C" void kernel_launch(void* const* d_in, const int* in_sizes, int n_in,
                              void* d_out, int out_size, void* d_ws, size_t ws_size,
                              hipStream_t stream) {
    const float* a1   = (const float*)d_in[0];
    const int*   len1 = (const int*)d_in[1];
    const float* a2   = (const float*)d_in[2];
    const int*   len2 = (const int*)d_in[3];
    const float* fcw  = (const float*)d_in[4];
    const float* fcb  = (const float*)d_in[5];
    const float* ww   = (const float*)d_in[6];
    float* out = (float*)d_out;

    fused_attn_pool_kernel<<<BB, 256, 0, stream>>>(a1, len1, a2, len2, fcw, fcb, ww, out);
}

// Round 2
// 42.466 us; speedup vs baseline: 3.5363x; 3.5363x over previous
//
#include <hip/hip_runtime.h>
#include <math.h>

#define BB 32
#define LL 128
#define DD 256
#define HH 1024   // 4*D

__device__ __forceinline__ float waveReduceSum(float v) {
#pragma unroll
    for (int m = 32; m >= 1; m >>= 1) v += __shfl_xor(v, m, 64);
    return v;
}
__device__ __forceinline__ float waveReduceMax(float v) {
#pragma unroll
    for (int m = 32; m >= 1; m >>= 1) v = fmaxf(v, __shfl_xor(v, m, 64));
    return v;
}

__device__ __forceinline__ float masked_we(float w) {
    return (fabsf(w) < 1e-7f) ? -1e7f : w;
}

// Kernel A: per batch -> s1, s2, softmax stats (gmax, rs, cs, dinv), pooled[D]
__global__ __launch_bounds__(256) void attn_pool_stats_kernel(
    const float* __restrict__ a1, const int* __restrict__ len1,
    const float* __restrict__ a2, const int* __restrict__ len2,
    const float* __restrict__ ww, float* __restrict__ wsP)
{
    const int b    = blockIdx.x;
    const int tid  = threadIdx.x;
    const int wave = tid >> 6;
    const int lane = tid & 63;

    __shared__ __align__(16) float4 wws4[DD / 4];
    __shared__ float s1[LL], s2[LL];
    __shared__ float rs[LL], cs[LL];
    __shared__ float part[256];
    __shared__ float redM[4], redS[4];
    __shared__ float gmax_s, dinv_s;

    const int l1 = len1[b];
    const int l2 = len2[b];

    if (tid < DD / 4) wws4[tid] = ((const float4*)ww)[tid];
    __syncthreads();

    const float* __restrict__ A1 = a1 + (size_t)b * LL * DD;
    const float* __restrict__ A2 = a2 + (size_t)b * LL * DD;

    // ---- phase 1: thread-per-row dot with ww (no cross-lane ops) ----
    {
        const float* row = (tid < LL) ? (A1 + (size_t)tid * DD)
                                      : (A2 + (size_t)(tid - LL) * DD);
        float ax = 0.f, ay = 0.f, az = 0.f, aw = 0.f;
#pragma unroll 8
        for (int d = 0; d < DD / 4; ++d) {
            const float4 v = ((const float4*)row)[d];
            const float4 w = wws4[d];
            ax += v.x * w.x; ay += v.y * w.y; az += v.z * w.z; aw += v.w * w.w;
        }
        const float s = (ax + ay) + (az + aw);
        if (tid < LL) s1[tid] = s; else s2[tid - LL] = s;
    }
    __syncthreads();

    const int i2    = tid >> 1;          // row for rs pass
    const int jbase = (tid & 1) * 64;

    // ---- phase 2: global max over masked scores (2 threads per row) ----
    {
        float m = -1e7f;                 // invalid / masked entries value
        if (i2 < l1) {
            const float si = s1[i2];
            float m0 = -1e7f, m1 = -1e7f, m2 = -1e7f, m3 = -1e7f;
#pragma unroll 4
            for (int k = 0; k < 64; k += 4) {
                const int j = jbase + k;
                if (j + 0 < l2) m0 = fmaxf(m0, masked_we(si - s2[j + 0]));
                if (j + 1 < l2) m1 = fmaxf(m1, masked_we(si - s2[j + 1]));
                if (j + 2 < l2) m2 = fmaxf(m2, masked_we(si - s2[j + 2]));
                if (j + 3 < l2) m3 = fmaxf(m3, masked_we(si - s2[j + 3]));
            }
            m = fmaxf(fmaxf(m0, m1), fmaxf(m2, m3));
        }
        m = waveReduceMax(m);
        if (lane == 0) redM[wave] = m;
    }
    __syncthreads();
    if (tid == 0)
        gmax_s = fmaxf(fmaxf(redM[0], redM[1]), fmaxf(redM[2], redM[3]));
    __syncthreads();
    const float gmax = gmax_s;

    // ---- phase 3a: row partial sums (2 threads per row) + denom reduce ----
    {
        float acc = 0.f;
        if (i2 < l1) {
            const float si = s1[i2];
            for (int k = 0; k < 64; ++k) {
                const int j = jbase + k;
                if (j < l2) acc += expf(masked_we(si - s2[j]) - gmax);
            }
        }
        part[tid] = acc;
        const float wsum = waveReduceSum(acc);
        if (lane == 0) redS[wave] = wsum;
    }
    __syncthreads();
    if (tid < LL) rs[tid] = part[2 * tid] + part[2 * tid + 1];
    if (tid == 0) {
        float denom = redS[0] + redS[1] + redS[2] + redS[3];
        denom += (float)(LL * LL - l1 * l2) * expf(-1e7f - gmax);
        dinv_s = 1.0f / denom;
    }

    // ---- phase 3b: col partial sums (2 threads per col), overlap compute ----
    const int j2    = tid >> 1;
    const int ibase = (tid & 1) * 64;
    float acc2 = 0.f;
    if (j2 < l2) {
        const float sj = s2[j2];
        for (int k = 0; k < 64; ++k) {
            const int i = ibase + k;
            if (i < l1) acc2 += expf(masked_we(s1[i] - sj) - gmax);
        }
    }
    __syncthreads();           // everyone done reading part (rs) before reuse
    part[tid] = acc2;
    __syncthreads();
    if (tid < LL) cs[tid] = part[2 * tid] + part[2 * tid + 1];
    __syncthreads();

    // ---- phase 4: pooled[d] (coalesced column access, L2-hot) ----
    {
        const int d0 = tid;
        float p = 0.f;
#pragma unroll 8
        for (int i = 0; i < LL; ++i)
            p += rs[i] * A1[i * DD + d0] - cs[i] * A2[i * DD + d0];
        wsP[(size_t)b * DD + d0] = p * dinv_s;
    }
}

// Kernel B: out[b,h] = tanh(dot(pooled[b], fcw[h]) + fcb[h]); thread-per-output
__global__ __launch_bounds__(256) void fc_tanh_kernel(
    const float* __restrict__ wsP, const float* __restrict__ fcw,
    const float* __restrict__ fcb, float* __restrict__ out)
{
    const int c = blockIdx.x;      // h-chunk 0..3
    const int b = blockIdx.y;      // batch
    const int tid = threadIdx.x;

    __shared__ __align__(16) float4 ps4[DD / 4];
    if (tid < DD / 4) ps4[tid] = ((const float4*)(wsP + (size_t)b * DD))[tid];
    __syncthreads();

    const int h = c * 256 + tid;
    const float* __restrict__ wrow = fcw + (size_t)h * DD;
    float ax = 0.f, ay = 0.f, az = 0.f, aw = 0.f;
#pragma unroll 8
    for (int d = 0; d < DD / 4; ++d) {
        const float4 v = ((const float4*)wrow)[d];
        const float4 p = ps4[d];
        ax += v.x * p.x; ay += v.y * p.y; az += v.z * p.z; aw += v.w * p.w;
    }
    out[(size_t)b * HH + h] = tanhf((ax + ay) + (az + aw) + fcb[h]);
}

extern "C" void kernel_launch(void* const* d_in, const int* in_sizes, int n_in,
                              void* d_out, int out_size, void* d_ws, size_t ws_size,
                              hipStream_t stream) {
    const float* a1   = (const float*)d_in[0];
    const int*   len1 = (const int*)d_in[1];
    const float* a2   = (const float*)d_in[2];
    const int*   len2 = (const int*)d_in[3];
    const float* fcw  = (const float*)d_in[4];
    const float* fcb  = (const float*)d_in[5];
    const float* ww   = (const float*)d_in[6];
    float* out = (float*)d_out;
    float* wsP = (float*)d_ws;     // 32*256 floats

    attn_pool_stats_kernel<<<BB, 256, 0, stream>>>(a1, len1, a2, len2, ww, wsP);
    fc_tanh_kernel<<<dim3(4, BB), 256, 0, stream>>>(wsP, fcw, fcb, out);
}

// Round 3
// 39.936 us; speedup vs baseline: 3.7603x; 1.0633x over previous
//
#include <hip/hip_runtime.h>
#include <math.h>

#define BB 32
#define LL 128
#define DD 256
#define HH 1024   // 4*D

__device__ __forceinline__ float waveReduceSum(float v) {
#pragma unroll
    for (int m = 32; m >= 1; m >>= 1) v += __shfl_xor(v, m, 64);
    return v;
}
__device__ __forceinline__ float waveReduceMax(float v) {
#pragma unroll
    for (int m = 32; m >= 1; m >>= 1) v = fmaxf(v, __shfl_xor(v, m, 64));
    return v;
}

__device__ __forceinline__ float masked_we(float w) {
    return (fabsf(w) < 1e-7f) ? -1e7f : w;
}

// ---------------- K1: s[row] = dot(row, ww) for all 8192 rows ----------------
// grid 256 blocks x 256 thr; 32 rows/block, 8 threads/row.
__global__ __launch_bounds__(256) void s_kernel(
    const float* __restrict__ a1, const float* __restrict__ a2,
    const float* __restrict__ ww, float* __restrict__ wsS)
{
    const int tid = threadIdx.x;
    const int rloc = tid >> 3;     // 0..31
    const int t    = tid & 7;      // 0..7

    __shared__ __align__(16) float4 wws4[DD / 4];
    if (tid < DD / 4) wws4[tid] = ((const float4*)ww)[tid];
    __syncthreads();

    const int row = blockIdx.x * 32 + rloc;          // 0..8191
    const float* __restrict__ base =
        ((row >> 12) == 0 ? a1 + (size_t)(row & 4095) * DD
                          : a2 + (size_t)(row & 4095) * DD);

    float ax = 0.f, ay = 0.f, az = 0.f, aw = 0.f;
#pragma unroll
    for (int k = 0; k < 8; ++k) {
        const float4 v = ((const float4*)base)[t * 8 + k];
        const float4 w = wws4[t * 8 + k];
        ax += v.x * w.x; ay += v.y * w.y; az += v.z * w.z; aw += v.w * w.w;
    }
    float s = (ax + ay) + (az + aw);
    s += __shfl_xor(s, 1, 64);
    s += __shfl_xor(s, 2, 64);
    s += __shfl_xor(s, 4, 64);
    if (t == 0) wsS[row] = s;
}

// ---------------- K2: per-batch softmax stats -> rs*dinv, cs*dinv ----------------
__global__ __launch_bounds__(256) void stats_kernel(
    const float* __restrict__ wsS, const int* __restrict__ len1,
    const int* __restrict__ len2, float* __restrict__ wsRC)
{
    const int b    = blockIdx.x;
    const int tid  = threadIdx.x;
    const int wave = tid >> 6;
    const int lane = tid & 63;

    __shared__ float s1[LL], s2[LL];
    __shared__ float rs[LL], cs[LL];
    __shared__ float part[256];
    __shared__ float redM[4], redS[4];
    __shared__ float gmax_s, dinv_s;

    const int l1 = len1[b];
    const int l2 = len2[b];

    if (tid < LL) s1[tid] = wsS[b * LL + tid];
    else          s2[tid - LL] = wsS[4096 + b * LL + (tid - LL)];
    __syncthreads();

    const int i2    = tid >> 1;
    const int jbase = (tid & 1) * 64;

    // global max over masked scores (2 threads per row)
    {
        float m = -1e7f;
        if (i2 < l1) {
            const float si = s1[i2];
            float m0 = -1e7f, m1 = -1e7f, m2 = -1e7f, m3 = -1e7f;
#pragma unroll 4
            for (int k = 0; k < 64; k += 4) {
                const int j = jbase + k;
                if (j + 0 < l2) m0 = fmaxf(m0, masked_we(si - s2[j + 0]));
                if (j + 1 < l2) m1 = fmaxf(m1, masked_we(si - s2[j + 1]));
                if (j + 2 < l2) m2 = fmaxf(m2, masked_we(si - s2[j + 2]));
                if (j + 3 < l2) m3 = fmaxf(m3, masked_we(si - s2[j + 3]));
            }
            m = fmaxf(fmaxf(m0, m1), fmaxf(m2, m3));
        }
        m = waveReduceMax(m);
        if (lane == 0) redM[wave] = m;
    }
    __syncthreads();
    if (tid == 0)
        gmax_s = fmaxf(fmaxf(redM[0], redM[1]), fmaxf(redM[2], redM[3]));
    __syncthreads();
    const float gmax = gmax_s;

    // row partial sums (2 threads per row) + denominator
    {
        float acc = 0.f;
        if (i2 < l1) {
            const float si = s1[i2];
            for (int k = 0; k < 64; ++k) {
                const int j = jbase + k;
                if (j < l2) acc += expf(masked_we(si - s2[j]) - gmax);
            }
        }
        part[tid] = acc;
        const float wsum = waveReduceSum(acc);
        if (lane == 0) redS[wave] = wsum;
    }
    __syncthreads();
    if (tid < LL) rs[tid] = part[2 * tid] + part[2 * tid + 1];
    if (tid == 0) {
        float denom = redS[0] + redS[1] + redS[2] + redS[3];
        denom += (float)(LL * LL - l1 * l2) * expf(-1e7f - gmax);
        dinv_s = 1.0f / denom;
    }

    // col partial sums (2 threads per col)
    const int j2    = tid >> 1;
    const int ibase = (tid & 1) * 64;
    float acc2 = 0.f;
    if (j2 < l2) {
        const float sj = s2[j2];
        for (int k = 0; k < 64; ++k) {
            const int i = ibase + k;
            if (i < l1) acc2 += expf(masked_we(s1[i] - sj) - gmax);
        }
    }
    __syncthreads();
    part[tid] = acc2;
    __syncthreads();
    if (tid < LL) cs[tid] = part[2 * tid] + part[2 * tid + 1];
    __syncthreads();

    const float dinv = dinv_s;
    if (tid < LL) wsRC[b * 256 + tid] = rs[tid] * dinv;
    else          wsRC[b * 256 + tid] = cs[tid - LL] * dinv;
}

// ---------------- K3: pooled[b,d] = sum_i rs'[i]*A1[i,d] - cs'[i]*A2[i,d] ----------------
// grid (8, 32): 32-d chunk per block; 256 thr = 8 row-groups x 32 d.
__global__ __launch_bounds__(256) void pooled_kernel(
    const float* __restrict__ a1, const float* __restrict__ a2,
    const float* __restrict__ wsRC, float* __restrict__ wsP)
{
    const int c   = blockIdx.x;
    const int b   = blockIdx.y;
    const int tid = threadIdx.x;
    const int d   = c * 32 + (tid & 31);
    const int g   = tid >> 5;                 // 0..7

    __shared__ float rc[256];
    __shared__ float part[256];
    rc[tid] = wsRC[b * 256 + tid];
    __syncthreads();

    const float* __restrict__ A1 = a1 + (size_t)b * LL * DD;
    const float* __restrict__ A2 = a2 + (size_t)b * LL * DD;

    float acc = 0.f;
#pragma unroll
    for (int k = 0; k < 16; ++k) {
        const int i = g * 16 + k;
        acc += rc[i] * A1[i * DD + d] - rc[LL + i] * A2[i * DD + d];
    }
    part[tid] = acc;
    __syncthreads();
    if (tid < 32) {
        float p = 0.f;
#pragma unroll
        for (int g2 = 0; g2 < 8; ++g2) p += part[g2 * 32 + tid];
        wsP[b * DD + c * 32 + tid] = p;
    }
}

// ---------------- K4: out[b,h] = tanh(dot(pooled[b], fcw[h]) + fcb[h]) ----------------
__global__ __launch_bounds__(256) void fc_tanh_kernel(
    const float* __restrict__ wsP, const float* __restrict__ fcw,
    const float* __restrict__ fcb, float* __restrict__ out)
{
    const int c = blockIdx.x;      // h-chunk 0..3
    const int b = blockIdx.y;      // batch
    const int tid = threadIdx.x;

    __shared__ __align__(16) float4 ps4[DD / 4];
    if (tid < DD / 4) ps4[tid] = ((const float4*)(wsP + (size_t)b * DD))[tid];
    __syncthreads();

    const int h = c * 256 + tid;
    const float* __restrict__ wrow = fcw + (size_t)h * DD;
    float ax = 0.f, ay = 0.f, az = 0.f, aw = 0.f;
#pragma unroll 8
    for (int d = 0; d < DD / 4; ++d) {
        const float4 v = ((const float4*)wrow)[d];
        const float4 p = ps4[d];
        ax += v.x * p.x; ay += v.y * p.y; az += v.z * p.z; aw += v.w * p.w;
    }
    out[(size_t)b * HH + h] = tanhf((ax + ay) + (az + aw) + fcb[h]);
}

extern "C" void kernel_launch(void* const* d_in, const int* in_sizes, int n_in,
                              void* d_out, int out_size, void* d_ws, size_t ws_size,
                              hipStream_t stream) {
    const float* a1   = (const float*)d_in[0];
    const int*   len1 = (const int*)d_in[1];
    const float* a2   = (const float*)d_in[2];
    const int*   len2 = (const int*)d_in[3];
    const float* fcw  = (const float*)d_in[4];
    const float* fcb  = (const float*)d_in[5];
    const float* ww   = (const float*)d_in[6];
    float* out = (float*)d_out;

    float* wsS  = (float*)d_ws;            // 8192 floats: s1|s2 per batch
    float* wsRC = wsS + 8192;              // 8192 floats: rs'*dinv | cs'*dinv
    float* wsP  = wsRC + 8192;             // 8192 floats: pooled

    s_kernel<<<256, 256, 0, stream>>>(a1, a2, ww, wsS);
    stats_kernel<<<BB, 256, 0, stream>>>(wsS, len1, len2, wsRC);
    pooled_kernel<<<dim3(8, BB), 256, 0, stream>>>(a1, a2, wsRC, wsP);
    fc_tanh_kernel<<<dim3(4, BB), 256, 0, stream>>>(wsP, fcw, fcb, out);
}